// Round 5
// baseline (34.536 us; speedup 1.0000x reference)
//
#include <hip/hip_runtime.h>

#define PH 7
#define PW 7
#define CPB 8            // channels per block
#define RROWS 20         // max region rows: Dy<=19 for this distribution (+guarded)
#define RF4 6            // float4s per row window
#define RCOLS (RF4 * 4)  // 24 cols >= Dx(19)+align slack(3)+1
#define CMS 8            // colmax row stride (7 used + 1 pad)

__global__ __launch_bounds__(256) void roipool_kernel(
    const float* __restrict__ feat,
    const float* __restrict__ rois,
    float* __restrict__ out,
    int C, int H, int W) {

    const int cg  = blockIdx.x;
    const int r   = blockIdx.y;
    const int c0  = cg * CPB;
    const int tid = threadIdx.x;

    __shared__ float cm[CPB][RROWS][CMS];   // colmax: 5120 B

    // ---- block-uniform ROI math (verbatim from passing R1/R4) ----
    const float RATIO = 1.0f / 32.0f;
    const int   b  = (int)rois[r * 5 + 0];
    const float x0 = fminf(fmaxf(floorf(rois[r * 5 + 1] * RATIO), 0.0f), (float)W);
    const float y0 = fminf(fmaxf(floorf(rois[r * 5 + 2] * RATIO), 0.0f), (float)H);
    const float x1 = fminf(fmaxf(floorf(rois[r * 5 + 3] * RATIO), 0.0f), (float)W);
    const float y1 = fminf(fmaxf(floorf(rois[r * 5 + 4] * RATIO), 0.0f), (float)H);
    const bool valid = (x1 > x0) && (y1 > y0);
    const float bin_h = (y1 - y0) * (1.0f / PH);
    const float bin_w = (x1 - x0) * (1.0f / PW);

    int ry0 = (int)(y0 + floorf(0.0f * bin_h));     ry0 = min(max(ry0, 0), H);
    int rye = (int)(y0 + ceilf((float)PH * bin_h)); rye = min(max(rye, 0), H);
    int rx0 = (int)(x0 + floorf(0.0f * bin_w));     rx0 = min(max(rx0, 0), W);
    const int RHs    = min(rye - ry0, RROWS);
    const int rx0a   = rx0 & ~3;
    const int Wf4    = W >> 2;
    const int x4base = rx0a >> 2;

    // ---- stage 1: lane = (channel, region row) -> 7 column-bin maxima ----
    {
        const int c_l = tid / RROWS;
        const int y   = tid % RROWS;
        if (valid && tid < CPB * RROWS && y < RHs) {
            float f[RCOLS];
            const float* rowp = feat + (((size_t)b * C + c0 + c_l) * H + (ry0 + y)) * (size_t)W;
            #pragma unroll
            for (int x4 = 0; x4 < RF4; ++x4) {
                const int x4g = min(x4base + x4, Wf4 - 1);   // stay inside the row
                *reinterpret_cast<float4*>(&f[x4 * 4]) =
                    *reinterpret_cast<const float4*>(rowp + (x4g << 2));
            }
            // NOTE: clamped (aliased) slots have gx = rx0a+x >= 64 >= xej -> never selected.
            const int rx0u = __builtin_amdgcn_readfirstlane(rx0a);
            #pragma unroll
            for (int j = 0; j < PW; ++j) {
                int xsj = min(max((int)(x0 + floorf((float)j * bin_w)), 0), W);
                int xej = min(max((int)(x0 + ceilf((float)(j + 1) * bin_w)), 0), W);
                xsj = __builtin_amdgcn_readfirstlane(xsj);
                xej = __builtin_amdgcn_readfirstlane(xej);
                float m = -INFINITY;
                #pragma unroll
                for (int x = 0; x < RCOLS; ++x) {            // static idx -> registers
                    const int gx = rx0u + x;
                    if (gx >= xsj && gx < xej) m = fmaxf(m, f[x]);
                }
                cm[c_l][y][j] = m;
            }
        }
    }
    __syncthreads();

    // ---- stage 2: lane = (channel, bin); max over colmax rows ----
    for (int o = tid; o < CPB * PH * PW; o += 256) {
        const int c_l = o / (PH * PW);
        const int ij  = o % (PH * PW);
        const int i   = ij / PW;
        const int j   = ij % PW;

        int ys = (int)(y0 + floorf((float)i * bin_h));
        int ye = (int)(y0 + ceilf((float)(i + 1) * bin_h));
        int xs = (int)(x0 + floorf((float)j * bin_w));
        int xe = (int)(x0 + ceilf((float)(j + 1) * bin_w));
        ys = min(max(ys, 0), H);
        ye = min(max(ye, 0), H);
        xs = min(max(xs, 0), W);
        xe = min(max(xe, 0), W);
        const bool ok = valid && (ye > ys) && (xe > xs);

        float m = -INFINITY;
        if (ok) {
            const bool staged = (ys >= ry0) && (ye <= ry0 + RHs) &&
                                (xs >= rx0a) && (xe - rx0a <= RCOLS);
            if (staged) {
                for (int y = ys; y < ye; ++y)
                    m = fmaxf(m, cm[c_l][y - ry0][j]);
            } else {
                // fallback: verbatim R1 global path (distribution-independent)
                const float* base = feat + ((size_t)b * C + c0 + c_l) * (size_t)(H * W);
                for (int y = ys; y < ye; ++y)
                    for (int x = xs; x < xe; ++x)
                        m = fmaxf(m, base[y * W + x]);
            }
        }
        out[((size_t)r * C + c0 + c_l) * (PH * PW) + ij] = ok ? m : 0.0f;
    }
}

extern "C" void kernel_launch(void* const* d_in, const int* in_sizes, int n_in,
                              void* d_out, int out_size, void* d_ws, size_t ws_size,
                              hipStream_t stream) {
    const float* feat = (const float*)d_in[0];
    const float* rois = (const float*)d_in[1];
    float* out = (float*)d_out;

    const int R = in_sizes[1] / 5;       // 128
    const int C = 256, H = 64, W = 64;   // per reference setup (N=4)

    dim3 grid(C / CPB, R);               // 32 x 128 = 4096 blocks
    roipool_kernel<<<grid, 256, 0, stream>>>(feat, rois, out, C, H, W);
}

// Round 6
// 25.555 us; speedup vs baseline: 1.3515x; 1.3515x over previous
//
#include <hip/hip_runtime.h>

#define PH 7
#define PW 7
#define CPB 8            // channels per block
#define RROWS 20         // max region rows for this distribution (guarded by fallback)
#define RF4 6            // float4 loads per staged row
#define RCOLS (RF4 * 4)  // 24 usable columns
#define LSTR 25          // padded LDS row stride (floats), coprime with 32 banks
#define CSTR 9           // padded colmax row stride (floats)

__global__ __launch_bounds__(256) void roipool_kernel(
    const float* __restrict__ feat,
    const float* __restrict__ rois,
    float* __restrict__ out,
    int C, int H, int W) {

    const int cg  = blockIdx.x;
    const int r   = blockIdx.y;
    const int c0  = cg * CPB;
    const int tid = threadIdx.x;

    __shared__ float lf[CPB][RROWS][LSTR];   // 16000 B feature window
    __shared__ float cm[CPB][RROWS][CSTR];   // 5760 B  column-bin maxima

    // ---- block-uniform ROI math (verbatim from passing R1/R4) ----
    const float RATIO = 1.0f / 32.0f;
    const int   b  = (int)rois[r * 5 + 0];
    const float x0 = fminf(fmaxf(floorf(rois[r * 5 + 1] * RATIO), 0.0f), (float)W);
    const float y0 = fminf(fmaxf(floorf(rois[r * 5 + 2] * RATIO), 0.0f), (float)H);
    const float x1 = fminf(fmaxf(floorf(rois[r * 5 + 3] * RATIO), 0.0f), (float)W);
    const float y1 = fminf(fmaxf(floorf(rois[r * 5 + 4] * RATIO), 0.0f), (float)H);
    const bool valid = (x1 > x0) && (y1 > y0);
    const float bin_h = (y1 - y0) * (1.0f / PH);
    const float bin_w = (x1 - x0) * (1.0f / PW);

    int ry0 = (int)(y0 + floorf(0.0f * bin_h));     ry0 = min(max(ry0, 0), H);
    int rye = (int)(y0 + ceilf((float)PH * bin_h)); rye = min(max(rye, 0), H);
    int rx0 = (int)(x0 + floorf(0.0f * bin_w));     rx0 = min(max(rx0, 0), W);
    const int RHs    = min(rye - ry0, RROWS);
    const int rx0a   = rx0 & ~3;
    const int Wf4    = W >> 2;
    const int x4base = rx0a >> 2;

    // ---- phase 1: stage window into padded LDS (coalesced float4 global loads) ----
    if (valid && RHs > 0) {
        for (int k = tid; k < CPB * RROWS * RF4; k += 256) {   // 960 items
            const int c_l = k / (RROWS * RF4);
            const int rem = k % (RROWS * RF4);
            const int y   = rem / RF4;
            const int x4  = rem % RF4;
            if (y < RHs) {
                const int x4g = min(x4base + x4, Wf4 - 1);     // clamp: aliased slots
                const float4 v = *reinterpret_cast<const float4*>(  // map to cols>=64,
                    feat + (((size_t)b * C + c0 + c_l) * H + (ry0 + y)) * (size_t)W // never read
                         + (x4g << 2));
                // scalar LDS writes (25-float rows are not 16B aligned)
                lf[c_l][y][x4 * 4 + 0] = v.x;
                lf[c_l][y][x4 * 4 + 1] = v.y;
                lf[c_l][y][x4 * 4 + 2] = v.z;
                lf[c_l][y][x4 * 4 + 3] = v.w;
            }
        }
    }
    __syncthreads();

    // ---- phase 2: colmax — one thread per (channel, region row) ----
    {
        const int c_l = tid / RROWS;
        const int y   = tid % RROWS;
        if (valid && tid < CPB * RROWS && y < RHs) {
            #pragma unroll
            for (int j = 0; j < PW; ++j) {
                int xsj = (int)(x0 + floorf((float)j * bin_w));
                int xej = (int)(x0 + ceilf((float)(j + 1) * bin_w));
                xsj = min(max(xsj, 0), W);
                xej = min(max(xej, 0), W);
                float m = -INFINITY;
                const int lo = max(xsj - rx0a, 0);
                const int hi = min(xej - rx0a, RCOLS);
                for (int x = lo; x < hi; ++x)           // conflict-free: y-stride 25
                    m = fmaxf(m, lf[c_l][y][x]);
                cm[c_l][y][j] = m;
            }
        }
    }
    __syncthreads();

    // ---- phase 3: row-bin max over colmax; coalesced output ----
    for (int o = tid; o < CPB * PH * PW; o += 256) {
        const int c_l = o / (PH * PW);
        const int ij  = o % (PH * PW);
        const int i   = ij / PW;
        const int j   = ij % PW;

        int ys = (int)(y0 + floorf((float)i * bin_h));
        int ye = (int)(y0 + ceilf((float)(i + 1) * bin_h));
        int xs = (int)(x0 + floorf((float)j * bin_w));
        int xe = (int)(x0 + ceilf((float)(j + 1) * bin_w));
        ys = min(max(ys, 0), H);
        ye = min(max(ye, 0), H);
        xs = min(max(xs, 0), W);
        xe = min(max(xe, 0), W);
        const bool ok = valid && (ye > ys) && (xe > xs);

        float m = -INFINITY;
        if (ok) {
            const bool staged = (ys >= ry0) && (ye <= ry0 + RHs) &&
                                (xs >= rx0a) && (xe - rx0a <= RCOLS);
            if (staged) {
                for (int y = ys; y < ye; ++y)           // <=4 reads
                    m = fmaxf(m, cm[c_l][y - ry0][j]);
            } else {
                // fallback: verbatim R1 global path (distribution-independent)
                const float* base = feat + ((size_t)b * C + c0 + c_l) * (size_t)(H * W);
                for (int y = ys; y < ye; ++y)
                    for (int x = xs; x < xe; ++x)
                        m = fmaxf(m, base[y * W + x]);
            }
        }
        out[((size_t)r * C + c0 + c_l) * (PH * PW) + ij] = ok ? m : 0.0f;
    }
}

extern "C" void kernel_launch(void* const* d_in, const int* in_sizes, int n_in,
                              void* d_out, int out_size, void* d_ws, size_t ws_size,
                              hipStream_t stream) {
    const float* feat = (const float*)d_in[0];
    const float* rois = (const float*)d_in[1];
    float* out = (float*)d_out;

    const int R = in_sizes[1] / 5;       // 128
    const int C = 256, H = 64, W = 64;   // per reference setup (N=4)

    dim3 grid(C / CPB, R);               // 32 x 128 = 4096 blocks
    roipool_kernel<<<grid, 256, 0, stream>>>(feat, rois, out, C, H, W);
}